// Round 9
// baseline (300.802 us; speedup 1.0000x reference)
//
#include <hip/hip_runtime.h>

namespace {
constexpr int Hh = 128, Ww = 128, HW = Hh * Ww;
constexpr int Bn = 4;

using h4 = __attribute__((ext_vector_type(4))) _Float16;
using h8 = __attribute__((ext_vector_type(8))) _Float16;
using f4 = __attribute__((ext_vector_type(4))) float;
using i4 = __attribute__((ext_vector_type(4))) int;
using g2 = __attribute__((ext_vector_type(2))) __fp16;

// ---- workspace layout (f32 slots) ----
constexpr size_t OFF_OFF  = 0;                       // 4*27*HW f32
constexpr size_t XH1_OFF  = OFF_OFF + (size_t)Bn*27*HW;        // 4*HW*64 f16
constexpr size_t OUT1_OFF = XH1_OFF + (size_t)Bn*HW*32;
constexpr size_t WA1_OFF  = OUT1_OFF + (size_t)Bn*HW*32;       // 9*64*64 f16
constexpr size_t WA2_OFF  = WA1_OFF + 18432;                   // 9*32*64 f16
constexpr size_t WO1_OFF  = WA2_OFF + 9216;
constexpr size_t WO2_OFF  = WO1_OFF + 9216;
constexpr size_t BN_OFF   = WO2_OFF + 9216;                    // 256 f32

constexpr int E1 = 9 * 64 * 64;   // wA1
constexpr int E2 = 9 * 32 * 64;   // wA2
constexpr int E3 = 9 * 32 * 64;   // wO1 (27 real rows, 5 zero pad)
constexpr int E4 = 9 * 32 * 64;   // wO2
constexpr int E5 = 256;           // bn: sc1[64] sh1[64] sc2[32] sh2[32] bo1[32] bo2[32]
constexpr int PREP_N = E1 + E2 + E3 + E4 + E5;

__global__ __launch_bounds__(256)
void prep_kernel(const float* __restrict__ w1, const float* __restrict__ w2,
                 const float* __restrict__ wo1, const float* __restrict__ wo2,
                 const float* __restrict__ g1, const float* __restrict__ be1,
                 const float* __restrict__ rm1, const float* __restrict__ rv1,
                 const float* __restrict__ g2v, const float* __restrict__ be2,
                 const float* __restrict__ rm2, const float* __restrict__ rv2,
                 const float* __restrict__ bo1, const float* __restrict__ bo2,
                 _Float16* __restrict__ wA1, _Float16* __restrict__ wA2,
                 _Float16* __restrict__ wO1, _Float16* __restrict__ wO2,
                 float* __restrict__ bn)
{
  int i = blockIdx.x * 256 + threadIdx.x;
  if (i < E1) {
    int c = i & 63, o = (i >> 6) & 63, k = i >> 12;
    wA1[i] = (_Float16)w1[(o * 64 + c) * 9 + k];
  } else if (i < E1 + E2) {
    int j = i - E1;
    int c = j & 63, o = (j >> 6) & 31, k = j >> 11;
    wA2[j] = (_Float16)w2[(o * 64 + c) * 9 + k];
  } else if (i < E1 + E2 + E3) {
    int j = i - (E1 + E2);
    int c = j & 63, o = (j >> 6) & 31, k = j >> 11;
    wO1[j] = (o < 27) ? (_Float16)wo1[(o * 64 + c) * 9 + k] : (_Float16)0.f;
  } else if (i < E1 + E2 + E3 + E4) {
    int j = i - (E1 + E2 + E3);
    int c = j & 63, o = (j >> 6) & 31, k = j >> 11;
    wO2[j] = (o < 27) ? (_Float16)wo2[(o * 64 + c) * 9 + k] : (_Float16)0.f;
  } else if (i < PREP_N) {
    int j = i - (E1 + E2 + E3 + E4);
    if (j < 64)       { bn[j] = g1[j] * rsqrtf(rv1[j] + 1e-5f); }
    else if (j < 128) { int c = j - 64;  float inv = g1[c] * rsqrtf(rv1[c] + 1e-5f); bn[j] = be1[c] - rm1[c] * inv; }
    else if (j < 160) { int c = j - 128; bn[j] = g2v[c] * rsqrtf(rv2[c] + 1e-5f); }
    else if (j < 192) { int c = j - 160; float inv = g2v[c] * rsqrtf(rv2[c] + 1e-5f); bn[j] = be2[c] - rm2[c] * inv; }
    else if (j < 224) { int c = j - 192; bn[j] = (c < 27) ? bo1[c] : 0.f; }
    else              { int c = j - 224; bn[j] = (c < 27) ? bo2[c] : 0.f; }
  }
}

// NCHW concat(pB,pA) -> NHWC fp16. Block = 64 px * 64 ch, LDS transpose.
__global__ __launch_bounds__(256)
void xcat_kernel(const float* __restrict__ pA, const float* __restrict__ pB,
                 _Float16* __restrict__ xh)
{
  __shared__ float tile[64][65];
  int t = threadIdx.x;
  int pxbase = blockIdx.x * 64;
  int b = pxbase >> 14, hwbase = pxbase & (HW - 1);
  int lane = t & 63, cq = t >> 6;
  #pragma unroll
  for (int i = 0; i < 16; i++) {
    int cc = i * 4 + cq;
    const float* src = (cc < 32) ? (pB + ((size_t)b * 32 + cc) * HW)
                                 : (pA + ((size_t)b * 32 + cc - 32) * HW);
    tile[lane][cc] = src[hwbase + lane];
  }
  __syncthreads();
  int px = t >> 2, cg = t & 3;
  h8 ra, rb;
  #pragma unroll
  for (int j = 0; j < 8; j++) {
    ra[j] = (_Float16)tile[px][cg * 16 + j];
    rb[j] = (_Float16)tile[px][cg * 16 + 8 + j];
  }
  _Float16* dst = xh + (size_t)(pxbase + px) * 64 + cg * 16;
  *(h8*)dst = ra;
  *(h8*)(dst + 8) = rb;
}

// 3x3 conv 64->27(pad32) via direct-global MFMA implicit GEMM.
__global__ __launch_bounds__(256)
void convoff_kernel(const _Float16* __restrict__ xh, const _Float16* __restrict__ wO,
                    const float* __restrict__ bo, float* __restrict__ offo)
{
  int t = threadIdx.x, wv = t >> 6, l = t & 63;
  int l15 = l & 15, lg = l >> 4;
  int pxbase = blockIdx.x * 64;
  int b = pxbase >> 14, hwbase = pxbase & (HW - 1);
  int h = hwbase >> 7, wb = hwbase & 127;
  int pxl = wv * 16 + l15;
  int wpix = wb + pxl;
  f4 acc0 = {0.f, 0.f, 0.f, 0.f};
  f4 acc1 = {0.f, 0.f, 0.f, 0.f};
  const _Float16* xrowbase = xh + (size_t)b * HW * 64;
  for (int k = 0; k < 9; k++) {
    int dy = k / 3 - 1, dx = k % 3 - 1;
    int yy = h + dy;
    if ((unsigned)yy >= 128u) continue;          // uniform per block
    int xx = wpix + dx;
    bool valid = (unsigned)xx < 128u;
    const _Float16* brow = xrowbase + ((size_t)yy * 128 + xx) * 64;
    #pragma unroll
    for (int kk = 0; kk < 2; kk++) {
      h8 bf = {(_Float16)0.f, (_Float16)0.f, (_Float16)0.f, (_Float16)0.f,
               (_Float16)0.f, (_Float16)0.f, (_Float16)0.f, (_Float16)0.f};
      if (valid) bf = *(const h8*)(brow + kk * 32 + lg * 8);
      const _Float16* arow = wO + ((size_t)k * 32 + l15) * 64 + kk * 32 + lg * 8;
      h8 af0 = *(const h8*)(arow);
      h8 af1 = *(const h8*)(arow + 16 * 64);
      acc0 = __builtin_amdgcn_mfma_f32_16x16x32_f16(af0, bf, acc0, 0, 0, 0);
      acc1 = __builtin_amdgcn_mfma_f32_16x16x32_f16(af1, bf, acc1, 0, 0, 0);
    }
  }
  int hwpx = hwbase + pxl;
  float* ob = offo + (size_t)b * 27 * HW + hwpx;
  int o0 = lg * 4;
  f4 b0 = *(const f4*)(bo + o0);
  #pragma unroll
  for (int r = 0; r < 4; r++) ob[(o0 + r) * HW] = acc0[r] + b0[r];
  int o1 = 16 + lg * 4;
  f4 b1 = *(const f4*)(bo + o1);
  #pragma unroll
  for (int r = 0; r < 4; r++) if (o1 + r < 27) ob[(o1 + r) * HW] = acc1[r] + b1[r];
}

// Modulated deformable conv: per-lane DIRECT B-fragment gather (no smem tile,
// no per-k barriers). Lane l: pixel = wv*16 + (l&15), channels (l>>4)*8 (+32).
// Per k: 4 corners x 2 kk f16x8 loads -> f32 lerp -> MFMA.
template<int M, bool FINAL>
__global__ __launch_bounds__(256)
void deform_kernel(const _Float16* __restrict__ xh, const float* __restrict__ offo,
                   const _Float16* __restrict__ wA,
                   const float* __restrict__ scale, const float* __restrict__ shift,
                   const float* __restrict__ Aatt, const float* __restrict__ Batt,
                   _Float16* __restrict__ outh, float* __restrict__ outf)
{
  __shared__ __align__(16) float sW[576 * 4];   // w00..w11 (mask folded)
  __shared__ __align__(16) int   sR[576 * 4];   // corner byte offsets
  int t = threadIdx.x, wv = t >> 6, l = t & 63;
  int l15 = l & 15, lg = l >> 4;
  int pxbase = blockIdx.x * 64;
  int b = pxbase >> 14, hwbase = pxbase & (HW - 1);
  int h = hwbase >> 7, wb = hwbase & 127;
  const float* offb = offo + (size_t)b * 27 * HW;
  const char* xbb = (const char*)(xh + (size_t)b * HW * 64);
  constexpr int MT = M / 16;
  f4 acc[MT];
  #pragma unroll
  for (int mt = 0; mt < MT; mt++) acc[mt] = f4{0.f, 0.f, 0.f, 0.f};

  // ---- setup phase: all 576 (k,px) bilinear configs, once ----
  for (int it = t; it < 576; it += 256) {
    int k = it >> 6, px = it & 63;
    int hwpx = hwbase + px;
    float dy = offb[(2 * k) * HW + hwpx];
    float dx = offb[(2 * k + 1) * HW + hwpx];
    float mm = offb[(18 + k) * HW + hwpx];
    float m = 1.f / (1.f + __expf(-mm));
    float ys = (float)(h + k / 3 - 1) + dy;
    float xs = (float)(wb + px + k % 3 - 1) + dx;
    float y0f = floorf(ys), x0f = floorf(xs);
    float fy = ys - y0f, fx = xs - x0f;
    int y0 = (int)y0f, x0 = (int)x0f;
    int y1 = y0 + 1, x1 = x0 + 1;
    float vy0 = ((unsigned)y0 < 128u) ? 1.f : 0.f;
    float vy1 = ((unsigned)y1 < 128u) ? 1.f : 0.f;
    float vx0 = ((unsigned)x0 < 128u) ? 1.f : 0.f;
    float vx1 = ((unsigned)x1 < 128u) ? 1.f : 0.f;
    int cy0 = min(max(y0, 0), 127), cy1 = min(max(y1, 0), 127);
    int cx0 = min(max(x0, 0), 127), cx1 = min(max(x1, 0), 127);
    sW[it * 4 + 0] = (1.f - fy) * (1.f - fx) * m * vy0 * vx0;
    sW[it * 4 + 1] = (1.f - fy) * fx * m * vy0 * vx1;
    sW[it * 4 + 2] = fy * (1.f - fx) * m * vy1 * vx0;
    sW[it * 4 + 3] = fy * fx * m * vy1 * vx1;
    sR[it * 4 + 0] = (cy0 * 128 + cx0) * 128;   // byte offsets into NHWC f16
    sR[it * 4 + 1] = (cy0 * 128 + cx1) * 128;
    sR[it * 4 + 2] = (cy1 * 128 + cx0) * 128;
    sR[it * 4 + 3] = (cy1 * 128 + cx1) * 128;
  }
  __syncthreads();

  int pxr = wv * 16 + l15;       // this lane's pixel in the MFMA tile
  int cboff = lg * 16;           // byte offset of this lane's 8-ch slice (kk=0)

  for (int k = 0; k < 9; k++) {
    int item = (k << 6) + pxr;
    f4 wgt = *(const f4*)&sW[item * 4];
    i4 rr  = *(const i4*)&sR[item * 4];
    const char* p0 = xbb + rr[0] + cboff;
    const char* p1 = xbb + rr[1] + cboff;
    const char* p2 = xbb + rr[2] + cboff;
    const char* p3 = xbb + rr[3] + cboff;
    h8 a0 = *(const h8*)p0,        a1 = *(const h8*)p1;
    h8 a2 = *(const h8*)p2,        a3 = *(const h8*)p3;
    h8 b0 = *(const h8*)(p0 + 64), b1 = *(const h8*)(p1 + 64);
    h8 b2 = *(const h8*)(p2 + 64), b3 = *(const h8*)(p3 + 64);
    h8 bf0, bf1;
    #pragma unroll
    for (int j = 0; j < 8; j++) {
      bf0[j] = (_Float16)(wgt[0] * (float)a0[j] + wgt[1] * (float)a1[j]
                        + wgt[2] * (float)a2[j] + wgt[3] * (float)a3[j]);
      bf1[j] = (_Float16)(wgt[0] * (float)b0[j] + wgt[1] * (float)b1[j]
                        + wgt[2] * (float)b2[j] + wgt[3] * (float)b3[j]);
    }
    const _Float16* wk = wA + (size_t)k * M * 64;
    #pragma unroll
    for (int mt = 0; mt < MT; mt++) {
      h8 af0 = *(const h8*)(wk + ((size_t)(mt * 16 + l15)) * 64 + lg * 8);
      acc[mt] = __builtin_amdgcn_mfma_f32_16x16x32_f16(af0, bf0, acc[mt], 0, 0, 0);
    }
    #pragma unroll
    for (int mt = 0; mt < MT; mt++) {
      h8 af1 = *(const h8*)(wk + ((size_t)(mt * 16 + l15)) * 64 + 32 + lg * 8);
      acc[mt] = __builtin_amdgcn_mfma_f32_16x16x32_f16(af1, bf1, acc[mt], 0, 0, 0);
    }
  }

  // ---- epilogue: BN + ReLU (+ attention), C-layout col=l&15(px), row=lg*4+r ----
  int pxl = wv * 16 + l15;
  int hwpx = hwbase + pxl;
  int pxg = pxbase + pxl;
  if (!FINAL) {
    #pragma unroll
    for (int mt = 0; mt < MT; mt++) {
      int o0 = mt * 16 + lg * 4;
      f4 sc = *(const f4*)(scale + o0);
      f4 sh = *(const f4*)(shift + o0);
      h4 o4;
      #pragma unroll
      for (int r = 0; r < 4; r++) {
        o4[r] = (_Float16)fmaxf(fmaf(acc[mt][r], sc[r], sh[r]), 0.f);
      }
      *(h4*)(outh + (size_t)pxg * 64 + o0) = o4;
    }
  } else {
    float fm = (1.f - Aatt[(size_t)b * HW + hwpx]) * Batt[(size_t)b * HW + hwpx];
    #pragma unroll
    for (int mt = 0; mt < MT; mt++) {
      int o0 = mt * 16 + lg * 4;
      f4 sc = *(const f4*)(scale + o0);
      f4 sh = *(const f4*)(shift + o0);
      #pragma unroll
      for (int r = 0; r < 4; r++) {
        float v = fmaxf(fmaf(acc[mt][r], sc[r], sh[r]), 0.f) * fm;
        outf[((size_t)b * 32 + o0 + r) * HW + hwpx] = v;
      }
    }
  }
}

} // namespace

extern "C" void kernel_launch(void* const* d_in, const int* in_sizes, int n_in,
                              void* d_out, int out_size, void* d_ws, size_t ws_size,
                              hipStream_t stream) {
  const float* pA   = (const float*)d_in[1];
  const float* pB   = (const float*)d_in[2];
  const float* Aatt = (const float*)d_in[3];
  const float* Batt = (const float*)d_in[4];
  const float* wo1  = (const float*)d_in[5];
  const float* bo1  = (const float*)d_in[6];
  const float* w1   = (const float*)d_in[7];
  const float* g1   = (const float*)d_in[8];
  const float* be1  = (const float*)d_in[9];
  const float* rm1  = (const float*)d_in[10];
  const float* rv1  = (const float*)d_in[11];
  const float* wo2  = (const float*)d_in[12];
  const float* bo2  = (const float*)d_in[13];
  const float* w2   = (const float*)d_in[14];
  const float* g2   = (const float*)d_in[15];
  const float* be2  = (const float*)d_in[16];
  const float* rm2  = (const float*)d_in[17];
  const float* rv2  = (const float*)d_in[18];

  float* ws = (float*)d_ws;
  float*     off   = ws + OFF_OFF;
  _Float16*  xh1   = (_Float16*)(ws + XH1_OFF);
  _Float16*  out1h = (_Float16*)(ws + OUT1_OFF);
  _Float16*  wA1   = (_Float16*)(ws + WA1_OFF);
  _Float16*  wA2   = (_Float16*)(ws + WA2_OFF);
  _Float16*  wO1   = (_Float16*)(ws + WO1_OFF);
  _Float16*  wO2   = (_Float16*)(ws + WO2_OFF);
  float*     bn    = ws + BN_OFF;
  float* sc1 = bn;       float* sh1 = bn + 64;
  float* sc2 = bn + 128; float* sh2 = bn + 160;
  float* bO1 = bn + 192; float* bO2 = bn + 224;

  prep_kernel<<<(PREP_N + 255) / 256, 256, 0, stream>>>(
      w1, w2, wo1, wo2, g1, be1, rm1, rv1, g2, be2, rm2, rv2,
      bo1, bo2, wA1, wA2, wO1, wO2, bn);

  xcat_kernel<<<1024, 256, 0, stream>>>(pA, pB, xh1);

  // stage 1
  convoff_kernel<<<1024, 256, 0, stream>>>(xh1, wO1, bO1, off);
  deform_kernel<64, false><<<1024, 256, 0, stream>>>(
      xh1, off, wA1, sc1, sh1, nullptr, nullptr, out1h, nullptr);

  // stage 2
  convoff_kernel<<<1024, 256, 0, stream>>>(out1h, wO2, bO2, off);
  deform_kernel<32, true><<<1024, 256, 0, stream>>>(
      out1h, off, wA2, sc2, sh2, Aatt, Batt, nullptr, (float*)d_out);
}

// Round 10
// 269.421 us; speedup vs baseline: 1.1165x; 1.1165x over previous
//
#include <hip/hip_runtime.h>

namespace {
constexpr int Hh = 128, Ww = 128, HW = Hh * Ww;
constexpr int Bn = 4;

using h4 = __attribute__((ext_vector_type(4))) _Float16;
using h8 = __attribute__((ext_vector_type(8))) _Float16;
using f4 = __attribute__((ext_vector_type(4))) float;
using i4 = __attribute__((ext_vector_type(4))) int;
using g2 = __attribute__((ext_vector_type(2))) __fp16;

// ---- workspace layout (f32 slots) ----
constexpr size_t OFF_OFF  = 0;                       // 4*27*HW f32
constexpr size_t XH1_OFF  = OFF_OFF + (size_t)Bn*27*HW;        // 4*HW*64 f16
constexpr size_t OUT1_OFF = XH1_OFF + (size_t)Bn*HW*32;
constexpr size_t WA1_OFF  = OUT1_OFF + (size_t)Bn*HW*32;       // 9*64*64 f16
constexpr size_t WA2_OFF  = WA1_OFF + 18432;                   // 9*32*64 f16
constexpr size_t WO1_OFF  = WA2_OFF + 9216;
constexpr size_t WO2_OFF  = WO1_OFF + 9216;
constexpr size_t BN_OFF   = WO2_OFF + 9216;                    // 256 f32

constexpr int E1 = 9 * 64 * 64;   // wA1
constexpr int E2 = 9 * 32 * 64;   // wA2
constexpr int E3 = 9 * 32 * 64;   // wO1 (27 real rows, 5 zero pad)
constexpr int E4 = 9 * 32 * 64;   // wO2
constexpr int E5 = 256;           // bn: sc1[64] sh1[64] sc2[32] sh2[32] bo1[32] bo2[32]
constexpr int PREP_N = E1 + E2 + E3 + E4 + E5;

__global__ __launch_bounds__(256)
void prep_kernel(const float* __restrict__ w1, const float* __restrict__ w2,
                 const float* __restrict__ wo1, const float* __restrict__ wo2,
                 const float* __restrict__ g1, const float* __restrict__ be1,
                 const float* __restrict__ rm1, const float* __restrict__ rv1,
                 const float* __restrict__ g2v, const float* __restrict__ be2,
                 const float* __restrict__ rm2, const float* __restrict__ rv2,
                 const float* __restrict__ bo1, const float* __restrict__ bo2,
                 _Float16* __restrict__ wA1, _Float16* __restrict__ wA2,
                 _Float16* __restrict__ wO1, _Float16* __restrict__ wO2,
                 float* __restrict__ bn)
{
  int i = blockIdx.x * 256 + threadIdx.x;
  if (i < E1) {
    int c = i & 63, o = (i >> 6) & 63, k = i >> 12;
    wA1[i] = (_Float16)w1[(o * 64 + c) * 9 + k];
  } else if (i < E1 + E2) {
    int j = i - E1;
    int c = j & 63, o = (j >> 6) & 31, k = j >> 11;
    wA2[j] = (_Float16)w2[(o * 64 + c) * 9 + k];
  } else if (i < E1 + E2 + E3) {
    int j = i - (E1 + E2);
    int c = j & 63, o = (j >> 6) & 31, k = j >> 11;
    wO1[j] = (o < 27) ? (_Float16)wo1[(o * 64 + c) * 9 + k] : (_Float16)0.f;
  } else if (i < E1 + E2 + E3 + E4) {
    int j = i - (E1 + E2 + E3);
    int c = j & 63, o = (j >> 6) & 31, k = j >> 11;
    wO2[j] = (o < 27) ? (_Float16)wo2[(o * 64 + c) * 9 + k] : (_Float16)0.f;
  } else if (i < PREP_N) {
    int j = i - (E1 + E2 + E3 + E4);
    if (j < 64)       { bn[j] = g1[j] * rsqrtf(rv1[j] + 1e-5f); }
    else if (j < 128) { int c = j - 64;  float inv = g1[c] * rsqrtf(rv1[c] + 1e-5f); bn[j] = be1[c] - rm1[c] * inv; }
    else if (j < 160) { int c = j - 128; bn[j] = g2v[c] * rsqrtf(rv2[c] + 1e-5f); }
    else if (j < 192) { int c = j - 160; float inv = g2v[c] * rsqrtf(rv2[c] + 1e-5f); bn[j] = be2[c] - rm2[c] * inv; }
    else if (j < 224) { int c = j - 192; bn[j] = (c < 27) ? bo1[c] : 0.f; }
    else              { int c = j - 224; bn[j] = (c < 27) ? bo2[c] : 0.f; }
  }
}

// NCHW concat(pB,pA) -> NHWC fp16. Block = 64 px * 64 ch, LDS transpose.
__global__ __launch_bounds__(256)
void xcat_kernel(const float* __restrict__ pA, const float* __restrict__ pB,
                 _Float16* __restrict__ xh)
{
  __shared__ float tile[64][65];
  int t = threadIdx.x;
  int pxbase = blockIdx.x * 64;
  int b = pxbase >> 14, hwbase = pxbase & (HW - 1);
  int lane = t & 63, cq = t >> 6;
  #pragma unroll
  for (int i = 0; i < 16; i++) {
    int cc = i * 4 + cq;
    const float* src = (cc < 32) ? (pB + ((size_t)b * 32 + cc) * HW)
                                 : (pA + ((size_t)b * 32 + cc - 32) * HW);
    tile[lane][cc] = src[hwbase + lane];
  }
  __syncthreads();
  int px = t >> 2, cg = t & 3;
  h8 ra, rb;
  #pragma unroll
  for (int j = 0; j < 8; j++) {
    ra[j] = (_Float16)tile[px][cg * 16 + j];
    rb[j] = (_Float16)tile[px][cg * 16 + 8 + j];
  }
  _Float16* dst = xh + (size_t)(pxbase + px) * 64 + cg * 16;
  *(h8*)dst = ra;
  *(h8*)(dst + 8) = rb;
}

// 3x3 conv 64->27(pad32) via direct-global MFMA implicit GEMM.
__global__ __launch_bounds__(256)
void convoff_kernel(const _Float16* __restrict__ xh, const _Float16* __restrict__ wO,
                    const float* __restrict__ bo, float* __restrict__ offo)
{
  int t = threadIdx.x, wv = t >> 6, l = t & 63;
  int l15 = l & 15, lg = l >> 4;
  int pxbase = blockIdx.x * 64;
  int b = pxbase >> 14, hwbase = pxbase & (HW - 1);
  int h = hwbase >> 7, wb = hwbase & 127;
  int pxl = wv * 16 + l15;
  int wpix = wb + pxl;
  f4 acc0 = {0.f, 0.f, 0.f, 0.f};
  f4 acc1 = {0.f, 0.f, 0.f, 0.f};
  const _Float16* xrowbase = xh + (size_t)b * HW * 64;
  for (int k = 0; k < 9; k++) {
    int dy = k / 3 - 1, dx = k % 3 - 1;
    int yy = h + dy;
    if ((unsigned)yy >= 128u) continue;          // uniform per block
    int xx = wpix + dx;
    bool valid = (unsigned)xx < 128u;
    const _Float16* brow = xrowbase + ((size_t)yy * 128 + xx) * 64;
    #pragma unroll
    for (int kk = 0; kk < 2; kk++) {
      h8 bf = {(_Float16)0.f, (_Float16)0.f, (_Float16)0.f, (_Float16)0.f,
               (_Float16)0.f, (_Float16)0.f, (_Float16)0.f, (_Float16)0.f};
      if (valid) bf = *(const h8*)(brow + kk * 32 + lg * 8);
      const _Float16* arow = wO + ((size_t)k * 32 + l15) * 64 + kk * 32 + lg * 8;
      h8 af0 = *(const h8*)(arow);
      h8 af1 = *(const h8*)(arow + 16 * 64);
      acc0 = __builtin_amdgcn_mfma_f32_16x16x32_f16(af0, bf, acc0, 0, 0, 0);
      acc1 = __builtin_amdgcn_mfma_f32_16x16x32_f16(af1, bf, acc1, 0, 0, 0);
    }
  }
  int hwpx = hwbase + pxl;
  float* ob = offo + (size_t)b * 27 * HW + hwpx;
  int o0 = lg * 4;
  f4 b0 = *(const f4*)(bo + o0);
  #pragma unroll
  for (int r = 0; r < 4; r++) ob[(o0 + r) * HW] = acc0[r] + b0[r];
  int o1 = 16 + lg * 4;
  f4 b1 = *(const f4*)(bo + o1);
  #pragma unroll
  for (int r = 0; r < 4; r++) if (o1 + r < 27) ob[(o1 + r) * HW] = acc1[r] + b1[r];
}

// Modulated deformable conv: coalesced gather -> wave-private LDS tile -> MFMA.
// 512 thr = 8 waves, 64 px/block. Waves wv and wv+4 pair on pixel tile (wv&3):
// kgrp0 does k=0..4, kgrp1 does k=5..8. NO per-k barriers (wave-private smem).
// Final f32 accumulator reduction via LDS (aliased over dead sW/sR region).
template<int M, bool FINAL>
__global__ __launch_bounds__(512, 8)
void deform_kernel(const _Float16* __restrict__ xh, const float* __restrict__ offo,
                   const _Float16* __restrict__ wA,
                   const float* __restrict__ scale, const float* __restrict__ shift,
                   const float* __restrict__ Aatt, const float* __restrict__ Batt,
                   _Float16* __restrict__ outh, float* __restrict__ outf)
{
  constexpr int MT = M / 16;
  __shared__ __align__(16) char pool[18432 + 16384];
  float* sW = (float*)pool;              // [0, 9216)      bilinear weights
  int*   sR = (int*)(pool + 9216);       // [9216, 18432)  corner byte offsets
  char*  smem = pool + 18432;            // [18432, 34816) 8 x 2048B wave tiles
  f4*    red  = (f4*)pool;               // aliases sW/sR after k-loop barrier

  int t = threadIdx.x, wv = t >> 6, l = t & 63;
  int l15 = l & 15, lg = l >> 4;
  int tile = wv & 3;                     // pixel sub-tile 0..3 (16 px each)
  int kgrp = wv >> 2;                    // 0: k=0..4, 1: k=5..8
  int pxbase = blockIdx.x * 64;
  int b = pxbase >> 14, hwbase = pxbase & (HW - 1);
  int h = hwbase >> 7, wb = hwbase & 127;
  const float* offb = offo + (size_t)b * 27 * HW;
  const char* xbb = (const char*)(xh + (size_t)b * HW * 64);
  f4 acc[MT];
  #pragma unroll
  for (int mt = 0; mt < MT; mt++) acc[mt] = f4{0.f, 0.f, 0.f, 0.f};

  // ---- setup phase: all 576 (k,px) bilinear configs, once ----
  for (int it = t; it < 576; it += 512) {
    int k = it >> 6, px = it & 63;
    int hwpx = hwbase + px;
    float dy = offb[(2 * k) * HW + hwpx];
    float dx = offb[(2 * k + 1) * HW + hwpx];
    float mm = offb[(18 + k) * HW + hwpx];
    float m = 1.f / (1.f + __expf(-mm));
    float ys = (float)(h + k / 3 - 1) + dy;
    float xs = (float)(wb + px + k % 3 - 1) + dx;
    float y0f = floorf(ys), x0f = floorf(xs);
    float fy = ys - y0f, fx = xs - x0f;
    int y0 = (int)y0f, x0 = (int)x0f;
    int y1 = y0 + 1, x1 = x0 + 1;
    float vy0 = ((unsigned)y0 < 128u) ? 1.f : 0.f;
    float vy1 = ((unsigned)y1 < 128u) ? 1.f : 0.f;
    float vx0 = ((unsigned)x0 < 128u) ? 1.f : 0.f;
    float vx1 = ((unsigned)x1 < 128u) ? 1.f : 0.f;
    int cy0 = min(max(y0, 0), 127), cy1 = min(max(y1, 0), 127);
    int cx0 = min(max(x0, 0), 127), cx1 = min(max(x1, 0), 127);
    sW[it * 4 + 0] = (1.f - fy) * (1.f - fx) * m * vy0 * vx0;
    sW[it * 4 + 1] = (1.f - fy) * fx * m * vy0 * vx1;
    sW[it * 4 + 2] = fy * (1.f - fx) * m * vy1 * vx0;
    sW[it * 4 + 3] = fy * fx * m * vy1 * vx1;
    sR[it * 4 + 0] = (cy0 * 128 + cx0) * 128;   // byte offsets into NHWC f16
    sR[it * 4 + 1] = (cy0 * 128 + cx1) * 128;
    sR[it * 4 + 2] = (cy1 * 128 + cx0) * 128;
    sR[it * 4 + 3] = (cy1 * 128 + cx1) * 128;
  }
  __syncthreads();

  int half = l >> 5;        // which of 2 pixels this lane serves in gather
  int cb = (l & 31) * 4;    // byte offset of f16x2 within the 128B channel row
  char* mytile = smem + wv * 2048;
  int kbeg = kgrp ? 5 : 0, kend = kgrp ? 9 : 5;

  for (int k = kbeg; k < kend; k++) {
    // ---- gather: 8 iters x 2 px, f16x2 per lane, f32 lerp (coalesced) ----
    #pragma unroll
    for (int i = 0; i < 8; i++) {
      int lpx = i * 2 + half;            // 0..15 local pixel
      int item = (k << 6) + tile * 16 + lpx;
      f4 wgt = *(const f4*)&sW[item * 4];
      i4 rr  = *(const i4*)&sR[item * 4];
      g2 v00 = *(const g2*)(xbb + rr[0] + cb);
      g2 v01 = *(const g2*)(xbb + rr[1] + cb);
      g2 v10 = *(const g2*)(xbb + rr[2] + cb);
      g2 v11 = *(const g2*)(xbb + rr[3] + cb);
      float lo = wgt[0] * (float)v00[0] + wgt[1] * (float)v01[0]
               + wgt[2] * (float)v10[0] + wgt[3] * (float)v11[0];
      float hi = wgt[0] * (float)v00[1] + wgt[1] * (float)v01[1]
               + wgt[2] * (float)v10[1] + wgt[3] * (float)v11[1];
      g2 pk = __builtin_amdgcn_cvt_pkrtz(lo, hi);
      unsigned wa = (unsigned)(lpx * 128 + (cb ^ ((lpx & 7) << 4)));
      *(g2*)(mytile + wa) = pk;
    }
    // ---- MFMA: this wave's pixel = tile*16 + l15 (wave-private LDS, no barrier) ----
    #pragma unroll
    for (int kk = 0; kk < 2; kk++) {
      unsigned ra = (unsigned)(l15 * 128 + ((kk * 64 + lg * 16) ^ ((l15 & 7) << 4)));
      h8 bf = *(const h8*)(mytile + ra);
      #pragma unroll
      for (int mt = 0; mt < MT; mt++) {
        h8 af = *(const h8*)(wA + ((size_t)k * M + mt * 16 + l15) * 64 + kk * 32 + lg * 8);
        acc[mt] = __builtin_amdgcn_mfma_f32_16x16x32_f16(af, bf, acc[mt], 0, 0, 0);
      }
    }
  }

  // ---- cross-wave-pair accumulator reduction through LDS ----
  __syncthreads();                       // all k-loops done; red may alias sW/sR
  if (kgrp == 1) {
    #pragma unroll
    for (int mt = 0; mt < MT; mt++) red[mt * 256 + tile * 64 + l] = acc[mt];
  }
  __syncthreads();
  if (kgrp == 0) {
    #pragma unroll
    for (int mt = 0; mt < MT; mt++) {
      f4 o = red[mt * 256 + tile * 64 + l];
      acc[mt] += o;
    }
    // ---- epilogue: BN + ReLU (+ attention), C-layout col=l15(px), row=lg*4+r ----
    int pxl = tile * 16 + l15;
    int hwpx = hwbase + pxl;
    int pxg = pxbase + pxl;
    if (!FINAL) {
      #pragma unroll
      for (int mt = 0; mt < MT; mt++) {
        int o0 = mt * 16 + lg * 4;
        f4 sc = *(const f4*)(scale + o0);
        f4 sh = *(const f4*)(shift + o0);
        h4 o4;
        #pragma unroll
        for (int r = 0; r < 4; r++) {
          o4[r] = (_Float16)fmaxf(fmaf(acc[mt][r], sc[r], sh[r]), 0.f);
        }
        *(h4*)(outh + (size_t)pxg * 64 + o0) = o4;
      }
    } else {
      float fm = (1.f - Aatt[(size_t)b * HW + hwpx]) * Batt[(size_t)b * HW + hwpx];
      #pragma unroll
      for (int mt = 0; mt < MT; mt++) {
        int o0 = mt * 16 + lg * 4;
        f4 sc = *(const f4*)(scale + o0);
        f4 sh = *(const f4*)(shift + o0);
        #pragma unroll
        for (int r = 0; r < 4; r++) {
          float v = fmaxf(fmaf(acc[mt][r], sc[r], sh[r]), 0.f) * fm;
          outf[((size_t)b * 32 + o0 + r) * HW + hwpx] = v;
        }
      }
    }
  }
}

} // namespace

extern "C" void kernel_launch(void* const* d_in, const int* in_sizes, int n_in,
                              void* d_out, int out_size, void* d_ws, size_t ws_size,
                              hipStream_t stream) {
  const float* pA   = (const float*)d_in[1];
  const float* pB   = (const float*)d_in[2];
  const float* Aatt = (const float*)d_in[3];
  const float* Batt = (const float*)d_in[4];
  const float* wo1  = (const float*)d_in[5];
  const float* bo1  = (const float*)d_in[6];
  const float* w1   = (const float*)d_in[7];
  const float* g1   = (const float*)d_in[8];
  const float* be1  = (const float*)d_in[9];
  const float* rm1  = (const float*)d_in[10];
  const float* rv1  = (const float*)d_in[11];
  const float* wo2  = (const float*)d_in[12];
  const float* bo2  = (const float*)d_in[13];
  const float* w2   = (const float*)d_in[14];
  const float* g2   = (const float*)d_in[15];
  const float* be2  = (const float*)d_in[16];
  const float* rm2  = (const float*)d_in[17];
  const float* rv2  = (const float*)d_in[18];

  float* ws = (float*)d_ws;
  float*     off   = ws + OFF_OFF;
  _Float16*  xh1   = (_Float16*)(ws + XH1_OFF);
  _Float16*  out1h = (_Float16*)(ws + OUT1_OFF);
  _Float16*  wA1   = (_Float16*)(ws + WA1_OFF);
  _Float16*  wA2   = (_Float16*)(ws + WA2_OFF);
  _Float16*  wO1   = (_Float16*)(ws + WO1_OFF);
  _Float16*  wO2   = (_Float16*)(ws + WO2_OFF);
  float*     bn    = ws + BN_OFF;
  float* sc1 = bn;       float* sh1 = bn + 64;
  float* sc2 = bn + 128; float* sh2 = bn + 160;
  float* bO1 = bn + 192; float* bO2 = bn + 224;

  prep_kernel<<<(PREP_N + 255) / 256, 256, 0, stream>>>(
      w1, w2, wo1, wo2, g1, be1, rm1, rv1, g2, be2, rm2, rv2,
      bo1, bo2, wA1, wA2, wO1, wO2, bn);

  xcat_kernel<<<1024, 256, 0, stream>>>(pA, pB, xh1);

  // stage 1
  convoff_kernel<<<1024, 256, 0, stream>>>(xh1, wO1, bO1, off);
  deform_kernel<64, false><<<1024, 512, 0, stream>>>(
      xh1, off, wA1, sc1, sh1, nullptr, nullptr, out1h, nullptr);

  // stage 2
  convoff_kernel<<<1024, 256, 0, stream>>>(out1h, wO2, bO2, off);
  deform_kernel<32, true><<<1024, 512, 0, stream>>>(
      out1h, off, wA2, sc2, sh2, Aatt, Batt, nullptr, (float*)d_out);
}

// Round 12
// 199.827 us; speedup vs baseline: 1.5053x; 1.3483x over previous
//
#include <hip/hip_runtime.h>

namespace {
constexpr int Hh = 128, Ww = 128, HW = Hh * Ww;
constexpr int Bn = 4;

using h4 = __attribute__((ext_vector_type(4))) _Float16;
using h8 = __attribute__((ext_vector_type(8))) _Float16;
using f4 = __attribute__((ext_vector_type(4))) float;
using i4 = __attribute__((ext_vector_type(4))) int;

// ---- workspace layout (f32 slots) ----
constexpr size_t OFF_OFF  = 0;                       // 4*27*HW f32
constexpr size_t XH1_OFF  = OFF_OFF + (size_t)Bn*27*HW;        // 4*HW*64 f16
constexpr size_t OUT1_OFF = XH1_OFF + (size_t)Bn*HW*32;
constexpr size_t WA1_OFF  = OUT1_OFF + (size_t)Bn*HW*32;       // 36864 f16
constexpr size_t WA2_OFF  = WA1_OFF + 18432;                   // 18432 f16
constexpr size_t WO1_OFF  = WA2_OFF + 9216;
constexpr size_t WO2_OFF  = WO1_OFF + 9216;
constexpr size_t BN_OFF   = WO2_OFF + 9216;                    // 256 f32

// fragment layouts: wf[((k*2+kk)*MT + mt)*64 + lane][j]  (8 halfs per lane)
//   row = mt*16 + (lane&15)  (output channel o)
//   ch  = kk*32 + (lane>>4)*8 + j (input channel)
constexpr int F1 = 9 * 2 * 4 * 64 * 8;   // 36864, M=64 (MT=4)
constexpr int F2 = 9 * 2 * 2 * 64 * 8;   // 18432, M=32 (MT=2)
constexpr int F3 = F2;                   // wO1 (rows >=27 zeroed)
constexpr int F4 = F2;                   // wO2
constexpr int F5 = 256;                  // bn: sc1 sh1 sc2 sh2 bo1 bo2
constexpr int PREP_N = F1 + F2 + F3 + F4 + F5;

__global__ __launch_bounds__(256)
void prep_kernel(const float* __restrict__ w1, const float* __restrict__ w2,
                 const float* __restrict__ wo1, const float* __restrict__ wo2,
                 const float* __restrict__ g1, const float* __restrict__ be1,
                 const float* __restrict__ rm1, const float* __restrict__ rv1,
                 const float* __restrict__ g2v, const float* __restrict__ be2,
                 const float* __restrict__ rm2, const float* __restrict__ rv2,
                 const float* __restrict__ bo1, const float* __restrict__ bo2,
                 _Float16* __restrict__ wA1, _Float16* __restrict__ wA2,
                 _Float16* __restrict__ wO1, _Float16* __restrict__ wO2,
                 float* __restrict__ bn)
{
  int i = blockIdx.x * 256 + threadIdx.x;
  if (i < F1) {
    int j = i & 7, l = (i >> 3) & 63, rest = i >> 9;
    int mt = rest & 3, kk = (rest >> 2) & 1, k = rest >> 3;
    int row = mt * 16 + (l & 15), ch = kk * 32 + (l >> 4) * 8 + j;
    wA1[i] = (_Float16)w1[(row * 64 + ch) * 9 + k];
  } else if (i < F1 + F2) {
    int q = i - F1;
    int j = q & 7, l = (q >> 3) & 63, rest = q >> 9;
    int mt = rest & 1, kk = (rest >> 1) & 1, k = rest >> 2;
    int row = mt * 16 + (l & 15), ch = kk * 32 + (l >> 4) * 8 + j;
    wA2[q] = (_Float16)w2[(row * 64 + ch) * 9 + k];
  } else if (i < F1 + F2 + F3) {
    int q = i - (F1 + F2);
    int j = q & 7, l = (q >> 3) & 63, rest = q >> 9;
    int mt = rest & 1, kk = (rest >> 1) & 1, k = rest >> 2;
    int row = mt * 16 + (l & 15), ch = kk * 32 + (l >> 4) * 8 + j;
    wO1[q] = (row < 27) ? (_Float16)wo1[(row * 64 + ch) * 9 + k] : (_Float16)0.f;
  } else if (i < F1 + F2 + F3 + F4) {
    int q = i - (F1 + F2 + F3);
    int j = q & 7, l = (q >> 3) & 63, rest = q >> 9;
    int mt = rest & 1, kk = (rest >> 1) & 1, k = rest >> 2;
    int row = mt * 16 + (l & 15), ch = kk * 32 + (l >> 4) * 8 + j;
    wO2[q] = (row < 27) ? (_Float16)wo2[(row * 64 + ch) * 9 + k] : (_Float16)0.f;
  } else if (i < PREP_N) {
    int j = i - (F1 + F2 + F3 + F4);
    if (j < 64)       { bn[j] = g1[j] * rsqrtf(rv1[j] + 1e-5f); }
    else if (j < 128) { int c = j - 64;  float inv = g1[c] * rsqrtf(rv1[c] + 1e-5f); bn[j] = be1[c] - rm1[c] * inv; }
    else if (j < 160) { int c = j - 128; bn[j] = g2v[c] * rsqrtf(rv2[c] + 1e-5f); }
    else if (j < 192) { int c = j - 160; float inv = g2v[c] * rsqrtf(rv2[c] + 1e-5f); bn[j] = be2[c] - rm2[c] * inv; }
    else if (j < 224) { int c = j - 192; bn[j] = (c < 27) ? bo1[c] : 0.f; }
    else              { int c = j - 224; bn[j] = (c < 27) ? bo2[c] : 0.f; }
  }
}

// NCHW concat(pB,pA) -> NHWC fp16. Block = 64 px * 64 ch, LDS transpose.
__global__ __launch_bounds__(256)
void xcat_kernel(const float* __restrict__ pA, const float* __restrict__ pB,
                 _Float16* __restrict__ xh)
{
  __shared__ float tile[64][65];
  int t = threadIdx.x;
  int pxbase = blockIdx.x * 64;
  int b = pxbase >> 14, hwbase = pxbase & (HW - 1);
  int lane = t & 63, cq = t >> 6;
  #pragma unroll
  for (int i = 0; i < 16; i++) {
    int cc = i * 4 + cq;
    const float* src = (cc < 32) ? (pB + ((size_t)b * 32 + cc) * HW)
                                 : (pA + ((size_t)b * 32 + cc - 32) * HW);
    tile[lane][cc] = src[hwbase + lane];
  }
  __syncthreads();
  int px = t >> 2, cg = t & 3;
  h8 ra, rb;
  #pragma unroll
  for (int j = 0; j < 8; j++) {
    ra[j] = (_Float16)tile[px][cg * 16 + j];
    rb[j] = (_Float16)tile[px][cg * 16 + 8 + j];
  }
  _Float16* dst = xh + (size_t)(pxbase + px) * 64 + cg * 16;
  *(h8*)dst = ra;
  *(h8*)(dst + 8) = rb;
}

// 3x3 conv 64->27(pad32): LDS row-stage (coalesced) + MFMA implicit GEMM.
// Block 256 = 4 waves; 64 px of one h-row; B from swizzled LDS, A coalesced.
__global__ __launch_bounds__(256, 4)
void convoff_kernel(const _Float16* __restrict__ xh, const _Float16* __restrict__ wOf,
                    const float* __restrict__ bo, float* __restrict__ offo)
{
  __shared__ __align__(16) char btile[3 * 66 * 128];   // rows h-1..h+1, x wb-1..wb+64
  int t = threadIdx.x, wv = t >> 6, l = t & 63;
  int l15 = l & 15, lg = l >> 4;
  int pxbase = blockIdx.x * 64;
  int b = pxbase >> 14, hwbase = pxbase & (HW - 1);
  int h = hwbase >> 7, wb = hwbase & 127;
  const _Float16* xbase = xh + (size_t)b * HW * 64;
  // ---- stage: 1584 x 16B chunks, zero-padded OOB ----
  for (int i = 0; i < 7; i++) {
    int c = i * 256 + t;
    if (c < 1584) {
      int slot = c & 7, pxi = (c >> 3) % 66, r = (c >> 3) / 66;
      int gx = wb - 1 + pxi, gy = h - 1 + r;
      h8 v = {};
      if (((unsigned)gx < 128u) && ((unsigned)gy < 128u))
        v = *(const h8*)(xbase + ((size_t)gy * 128 + gx) * 64 + slot * 8);
      *(h8*)(btile + (r * 66 + pxi) * 128 + ((slot ^ (pxi & 7)) * 16)) = v;
    }
  }
  __syncthreads();

  f4 acc0 = {0.f, 0.f, 0.f, 0.f};
  f4 acc1 = {0.f, 0.f, 0.f, 0.f};
  int pxl = wv * 16 + l15;
  for (int k = 0; k < 9; k++) {
    int r = k / 3, dx = k % 3 - 1;
    int pxt = pxl + dx + 1;              // 0..65
    #pragma unroll
    for (int kk = 0; kk < 2; kk++) {
      int slot = kk * 4 + lg;
      h8 bf = *(const h8*)(btile + (r * 66 + pxt) * 128 + ((slot ^ (pxt & 7)) * 16));
      const _Float16* ab = wOf + (((size_t)(k * 2 + kk) * 2) * 64 + l) * 8;
      h8 af0 = *(const h8*)(ab);
      h8 af1 = *(const h8*)(ab + 512);   // mt=1
      acc0 = __builtin_amdgcn_mfma_f32_16x16x32_f16(af0, bf, acc0, 0, 0, 0);
      acc1 = __builtin_amdgcn_mfma_f32_16x16x32_f16(af1, bf, acc1, 0, 0, 0);
    }
  }
  int hwpx = hwbase + pxl;
  float* ob = offo + (size_t)b * 27 * HW + hwpx;
  int o0 = lg * 4;
  f4 b0 = *(const f4*)(bo + o0);
  #pragma unroll
  for (int r = 0; r < 4; r++) ob[(o0 + r) * HW] = acc0[r] + b0[r];
  int o1 = 16 + lg * 4;
  f4 b1 = *(const f4*)(bo + o1);
  #pragma unroll
  for (int r = 0; r < 4; r++) if (o1 + r < 27) ob[(o1 + r) * HW] = acc1[r] + b1[r];
}

// Modulated deformable conv: dwordx4 coalesced gather -> wave-private swizzled
// LDS tile -> MFMA. 256 thr = 4 waves, 64 px/block, barrier-free k-loop.
template<int M, bool FINAL>
__global__ __launch_bounds__(256, 4)
void deform_kernel(const _Float16* __restrict__ xh, const float* __restrict__ offo,
                   const _Float16* __restrict__ wAf,
                   const float* __restrict__ scale, const float* __restrict__ shift,
                   const float* __restrict__ Aatt, const float* __restrict__ Batt,
                   _Float16* __restrict__ outh, float* __restrict__ outf)
{
  constexpr int MT = M / 16;
  __shared__ __align__(16) char pool[18432 + 4 * 2048];
  float* sW = (float*)pool;              // [0,9216)     bilinear weights*mask
  int*   sR = (int*)(pool + 9216);       // [9216,18432) corner byte offsets
  char*  smem = pool + 18432;            // 4 x 2048B wave-private tiles

  int t = threadIdx.x, wv = t >> 6, l = t & 63;
  int l15 = l & 15, lg = l >> 4;
  int pxbase = blockIdx.x * 64;
  int b = pxbase >> 14, hwbase = pxbase & (HW - 1);
  int h = hwbase >> 7, wb = hwbase & 127;
  const float* offb = offo + (size_t)b * 27 * HW;
  const char* xbb = (const char*)(xh + (size_t)b * HW * 64);
  f4 acc[MT];
  #pragma unroll
  for (int mt = 0; mt < MT; mt++) acc[mt] = f4{0.f, 0.f, 0.f, 0.f};

  // ---- setup: all 576 (k,px) bilinear configs ----
  for (int it = t; it < 576; it += 256) {
    int k = it >> 6, px = it & 63;
    int hwpx = hwbase + px;
    float dy = offb[(2 * k) * HW + hwpx];
    float dx = offb[(2 * k + 1) * HW + hwpx];
    float mm = offb[(18 + k) * HW + hwpx];
    float m = 1.f / (1.f + __expf(-mm));
    float ys = (float)(h + k / 3 - 1) + dy;
    float xs = (float)(wb + px + k % 3 - 1) + dx;
    float y0f = floorf(ys), x0f = floorf(xs);
    float fy = ys - y0f, fx = xs - x0f;
    int y0 = (int)y0f, x0 = (int)x0f;
    int y1 = y0 + 1, x1 = x0 + 1;
    float vy0 = ((unsigned)y0 < 128u) ? 1.f : 0.f;
    float vy1 = ((unsigned)y1 < 128u) ? 1.f : 0.f;
    float vx0 = ((unsigned)x0 < 128u) ? 1.f : 0.f;
    float vx1 = ((unsigned)x1 < 128u) ? 1.f : 0.f;
    int cy0 = min(max(y0, 0), 127), cy1 = min(max(y1, 0), 127);
    int cx0 = min(max(x0, 0), 127), cx1 = min(max(x1, 0), 127);
    sW[it * 4 + 0] = (1.f - fy) * (1.f - fx) * m * vy0 * vx0;
    sW[it * 4 + 1] = (1.f - fy) * fx * m * vy0 * vx1;
    sW[it * 4 + 2] = fy * (1.f - fx) * m * vy1 * vx0;
    sW[it * 4 + 3] = fy * fx * m * vy1 * vx1;
    sR[it * 4 + 0] = (cy0 * 128 + cx0) * 128;
    sR[it * 4 + 1] = (cy0 * 128 + cx1) * 128;
    sR[it * 4 + 2] = (cy1 * 128 + cx0) * 128;
    sR[it * 4 + 3] = (cy1 * 128 + cx1) * 128;
  }
  __syncthreads();

  char* mytile = smem + wv * 2048;
  int gpx = l >> 3;          // gather: lane-group pixel 0..7
  int slot = l & 7;          // gather: 8-channel slot (16B)

  for (int k = 0; k < 9; k++) {
    // ---- gather: 2 iters x 8 px, f16x8/lane (128B-contig per px row) ----
    #pragma unroll
    for (int i = 0; i < 2; i++) {
      int pxl = i * 8 + gpx;             // 0..15 within wave tile
      int item = (k << 6) + wv * 16 + pxl;
      f4 wgt = *(const f4*)&sW[item * 4];
      i4 rr  = *(const i4*)&sR[item * 4];
      h8 a0 = *(const h8*)(xbb + rr[0] + slot * 16);
      h8 a1 = *(const h8*)(xbb + rr[1] + slot * 16);
      h8 a2 = *(const h8*)(xbb + rr[2] + slot * 16);
      h8 a3 = *(const h8*)(xbb + rr[3] + slot * 16);
      h8 ov;
      #pragma unroll
      for (int j = 0; j < 8; j++) {
        ov[j] = (_Float16)(wgt[0] * (float)a0[j] + wgt[1] * (float)a1[j]
                         + wgt[2] * (float)a2[j] + wgt[3] * (float)a3[j]);
      }
      *(h8*)(mytile + pxl * 128 + ((slot ^ (pxl & 7)) * 16)) = ov;
    }
    // ---- MFMA (wave-private LDS, no barrier) ----
    #pragma unroll
    for (int kk = 0; kk < 2; kk++) {
      int rslot = kk * 4 + lg;
      h8 bf = *(const h8*)(mytile + l15 * 128 + ((rslot ^ (l15 & 7)) * 16));
      #pragma unroll
      for (int mt = 0; mt < MT; mt++) {
        h8 af = *(const h8*)(wAf + (((size_t)(k * 2 + kk) * MT + mt) * 64 + l) * 8);
        acc[mt] = __builtin_amdgcn_mfma_f32_16x16x32_f16(af, bf, acc[mt], 0, 0, 0);
      }
    }
  }

  // ---- epilogue: BN + ReLU (+ attention), C: col=l15(px), row=lg*4+r ----
  int pxl = wv * 16 + l15;
  int hwpx = hwbase + pxl;
  int pxg = pxbase + pxl;
  if (!FINAL) {
    #pragma unroll
    for (int mt = 0; mt < MT; mt++) {
      int o0 = mt * 16 + lg * 4;
      f4 sc = *(const f4*)(scale + o0);
      f4 sh = *(const f4*)(shift + o0);
      h4 o4;
      #pragma unroll
      for (int r = 0; r < 4; r++) {
        o4[r] = (_Float16)fmaxf(fmaf(acc[mt][r], sc[r], sh[r]), 0.f);
      }
      *(h4*)(outh + (size_t)pxg * 64 + o0) = o4;
    }
  } else {
    float fm = (1.f - Aatt[(size_t)b * HW + hwpx]) * Batt[(size_t)b * HW + hwpx];
    #pragma unroll
    for (int mt = 0; mt < MT; mt++) {
      int o0 = mt * 16 + lg * 4;
      f4 sc = *(const f4*)(scale + o0);
      f4 sh = *(const f4*)(shift + o0);
      #pragma unroll
      for (int r = 0; r < 4; r++) {
        float v = fmaxf(fmaf(acc[mt][r], sc[r], sh[r]), 0.f) * fm;
        outf[((size_t)b * 32 + o0 + r) * HW + hwpx] = v;
      }
    }
  }
}

} // namespace

extern "C" void kernel_launch(void* const* d_in, const int* in_sizes, int n_in,
                              void* d_out, int out_size, void* d_ws, size_t ws_size,
                              hipStream_t stream) {
  const float* pA   = (const float*)d_in[1];
  const float* pB   = (const float*)d_in[2];
  const float* Aatt = (const float*)d_in[3];
  const float* Batt = (const float*)d_in[4];
  const float* wo1  = (const float*)d_in[5];
  const float* bo1  = (const float*)d_in[6];
  const float* w1   = (const float*)d_in[7];
  const float* g1   = (const float*)d_in[8];
  const float* be1  = (const float*)d_in[9];
  const float* rm1  = (const float*)d_in[10];
  const float* rv1  = (const float*)d_in[11];
  const float* wo2  = (const float*)d_in[12];
  const float* bo2  = (const float*)d_in[13];
  const float* w2   = (const float*)d_in[14];
  const float* g2   = (const float*)d_in[15];
  const float* be2  = (const float*)d_in[16];
  const float* rm2  = (const float*)d_in[17];
  const float* rv2  = (const float*)d_in[18];

  float* ws = (float*)d_ws;
  float*     off   = ws + OFF_OFF;
  _Float16*  xh1   = (_Float16*)(ws + XH1_OFF);
  _Float16*  out1h = (_Float16*)(ws + OUT1_OFF);
  _Float16*  wA1   = (_Float16*)(ws + WA1_OFF);
  _Float16*  wA2   = (_Float16*)(ws + WA2_OFF);
  _Float16*  wO1   = (_Float16*)(ws + WO1_OFF);
  _Float16*  wO2   = (_Float16*)(ws + WO2_OFF);
  float*     bn    = ws + BN_OFF;
  float* sc1 = bn;       float* sh1 = bn + 64;
  float* sc2 = bn + 128; float* sh2 = bn + 160;
  float* bO1 = bn + 192; float* bO2 = bn + 224;

  prep_kernel<<<(PREP_N + 255) / 256, 256, 0, stream>>>(
      w1, w2, wo1, wo2, g1, be1, rm1, rv1, g2, be2, rm2, rv2,
      bo1, bo2, wA1, wA2, wO1, wO2, bn);

  xcat_kernel<<<1024, 256, 0, stream>>>(pA, pB, xh1);

  // stage 1
  convoff_kernel<<<1024, 256, 0, stream>>>(xh1, wO1, bO1, off);
  deform_kernel<64, false><<<1024, 256, 0, stream>>>(
      xh1, off, wA1, sc1, sh1, nullptr, nullptr, out1h, nullptr);

  // stage 2
  convoff_kernel<<<1024, 256, 0, stream>>>(out1h, wO2, bO2, off);
  deform_kernel<32, true><<<1024, 256, 0, stream>>>(
      out1h, off, wA2, sc2, sh2, Aatt, Batt, nullptr, (float*)d_out);
}